// Round 1
// baseline (2170.172 us; speedup 1.0000x reference)
//
#include <hip/hip_runtime.h>

#define B_   8
#define N_   8192
#define CIN  64
#define COUT 128
#define M_   2048
#define K_   16

typedef float v2f __attribute__((ext_vector_type(2)));

// ---------------------------------------------------------------------------
// DPP wave-64 reduce helpers (VALU-only, no LDS latency).
// ---------------------------------------------------------------------------
template <int CTRL>
__device__ __forceinline__ unsigned long long dpp64(unsigned long long x) {
  int lo = (int)(unsigned)(x & 0xFFFFFFFFull);
  int hi = (int)(unsigned)(x >> 32);
  int dlo = __builtin_amdgcn_update_dpp(lo, lo, CTRL, 0xF, 0xF, false);
  int dhi = __builtin_amdgcn_update_dpp(hi, hi, CTRL, 0xF, 0xF, false);
  return ((unsigned long long)(unsigned)dhi << 32) | (unsigned)dlo;
}

__device__ __forceinline__ unsigned long long readlane_u64(unsigned long long k, int l) {
  unsigned lo = (unsigned)__builtin_amdgcn_readlane((int)(unsigned)(k & 0xFFFFFFFFull), l);
  unsigned hi = (unsigned)__builtin_amdgcn_readlane((int)(unsigned)(k >> 32), l);
  return ((unsigned long long)hi << 32) | lo;
}

__device__ __forceinline__ unsigned long long wave_min_u64(unsigned long long k) {
  unsigned long long t;
  t = dpp64<0x111>(k); k = t < k ? t : k;
  t = dpp64<0x112>(k); k = t < k ? t : k;
  t = dpp64<0x114>(k); k = t < k ? t : k;
  t = dpp64<0x118>(k); k = t < k ? t : k;
  t = dpp64<0x142>(k); k = t < k ? t : k;
  t = dpp64<0x143>(k); k = t < k ? t : k;
  return readlane_u64(k, 63);
}

// ---------------------------------------------------------------------------
// 1+2) Merged FPS + MLP kernel. Blocks 0..7: FPS (one per batch). Blocks
//      8..2055: MLP tiles (32 rows each) — they fill the other 248 CUs while
//      the 8 FPS blocks grind, hiding the MLP entirely.
//      Shared-mem union sized for FPS (136.5 KB -> 1 block/CU either kind).
//
//      FPS numerics identical to the passing chain: f32 strict numpy order
//      ((dx^2+dy^2)+dz^2) NO-FMA (contract off; pk ops are element-wise IEEE
//      identical), fminf, u64 (d<<32)|(N-1-n) argmax = (max d, min n).
//      R12: per-lane argmax is now a depth-4 u64-key max TREE (identical
//      selection semantics: equal d -> larger lo word = smaller n = first in
//      ascending-k order, exactly like the old strict-> serial scan), the
//      per-wave DPP reduce result is written by lane 63 directly (no
//      readlane round trip), and the decode reads back only the low dword.
//
//      MLP numerics identical: ascending-c4 float4 chunks, inner
//      4-term order xv.x*w0 + xv.y*w1 + xv.z*w2 + xv.w*w3.
// ---------------------------------------------------------------------------
#define FTH 512
#define FPT 16    // points per thread = N_/FTH
#define MROWS2 32 // rows per mlp block (512 threads)

__global__ __launch_bounds__(512) void fps_mlp_kernel(
    const float* __restrict__ p, float* __restrict__ p_out,
    const float* __restrict__ x, const float* __restrict__ W,
    const float* __restrict__ gamma, const float* __restrict__ beta,
    const float* __restrict__ rmean, const float* __restrict__ rvar,
    float* __restrict__ h) {
#pragma clang fp contract(off)
  __shared__ __align__(16) unsigned char smem[139776];

  const int tid = threadIdx.x;

  if (blockIdx.x >= 8) {
    // ---------------- MLP tile ----------------
    float* wt = (float*)smem;                   // W^T padded: wt[c*132+o]
    float* xs = (float*)(smem + 33792);         // xs[r*64+c], 32 rows

    const int o  = tid & 127;
    const int rg = tid >> 7;                    // 0..3 -> rows rg*8..rg*8+7
    const int rowBase = (blockIdx.x - 8) * MROWS2;

    for (int idx = tid; idx < COUT * CIN; idx += 512) {
      const int oo = idx >> 6, cc = idx & 63;
      wt[cc * 132 + oo] = W[idx];
    }
    ((float4*)xs)[tid] = ((const float4*)(x + (size_t)rowBase * CIN))[tid];
    __syncthreads();

    float acc[8] = {0.f, 0.f, 0.f, 0.f, 0.f, 0.f, 0.f, 0.f};
#pragma unroll
    for (int c4 = 0; c4 < CIN / 4; c4++) {
      const float w0 = wt[(4 * c4 + 0) * 132 + o];
      const float w1 = wt[(4 * c4 + 1) * 132 + o];
      const float w2 = wt[(4 * c4 + 2) * 132 + o];
      const float w3 = wt[(4 * c4 + 3) * 132 + o];
#pragma unroll
      for (int i = 0; i < 8; i++) {
        const float4 xv = *(const float4*)&xs[(rg * 8 + i) * CIN + c4 * 4];
        acc[i] += xv.x * w0 + xv.y * w1 + xv.z * w2 + xv.w * w3;
      }
    }
    const float mu = rmean[o];
    const float sc = rsqrtf(rvar[o] + 1e-5f) * gamma[o];
    const float bt = beta[o];
#pragma unroll
    for (int i = 0; i < 8; i++) {
      const float v = (acc[i] - mu) * sc + bt;
      h[(size_t)(rowBase + rg * 8 + i) * COUT + o] = fmaxf(v, 0.f);
    }
    return;
  }

  // ---------------- FPS ----------------
  float4* pc4 = (float4*)smem;                               // 128 KB
  unsigned long long (*wred)[8] =
      (unsigned long long (*)[8])(smem + 131072);            // 2*8*8 B
  int* idxHist = (int*)(smem + 131072 + 128);                // 8 KB

  const int b  = blockIdx.x;
  const int wv = tid >> 6;
  const int ln = tid & 63;

  const float* pb = p + (size_t)b * N_ * 3;
  for (int n = tid; n < N_; n += FTH)
    pc4[n] = make_float4(pb[3 * n + 0], pb[3 * n + 1], pb[3 * n + 2], 0.f);
  if (tid == 0) idxHist[0] = 0;
  __syncthreads();

  float4 c0 = pc4[0];
  float cx = c0.x, cy = c0.y, cz = c0.z;

  // pairs: element e of pair j is point n = tid + (2j+e)*512
  v2f X2[8], Y2[8], Z2[8], D2[8];
#pragma unroll
  for (int j = 0; j < 8; j++) {
    float4 a = pc4[tid + (2 * j) * FTH];
    float4 c = pc4[tid + (2 * j + 1) * FTH];
    X2[j] = (v2f){a.x, c.x};
    Y2[j] = (v2f){a.y, c.y};
    Z2[j] = (v2f){a.z, c.z};
    D2[j] = (v2f){__builtin_inff(), __builtin_inff()};
  }

  // precomputed low key words: lo32[e] = N-1-n for slot e (n = tid + e*512)
  unsigned lo32[16];
#pragma unroll
  for (int e = 0; e < 16; e++) lo32[e] = (unsigned)(N_ - 1 - tid - (e << 9));

  int buf = 0;
  for (int it = 1; it < M_; ++it) {
    const v2f cxv = {cx, cx}, cyv = {cy, cy}, czv = {cz, cz};
    unsigned long long kp[8];
#pragma unroll
    for (int j = 0; j < 8; j++) {
      v2f dx = X2[j] - cxv;
      v2f dy = Y2[j] - cyv;
      v2f dz = Z2[j] - czv;
      v2f m1 = dx * dx;
      v2f m2 = dy * dy;
      v2f s  = m1 + m2;
      v2f m3 = dz * dz;
      v2f d  = s + m3;                           // numpy order, no fma
      v2f dm = __builtin_elementwise_min(D2[j], d);
      D2[j] = dm;
      const unsigned long long ka =
          ((unsigned long long)__float_as_uint(dm.x) << 32) | (unsigned long long)lo32[2 * j];
      const unsigned long long kb =
          ((unsigned long long)__float_as_uint(dm.y) << 32) | (unsigned long long)lo32[2 * j + 1];
      kp[j] = ka > kb ? ka : kb;   // tie: larger lo = smaller n (x before y)
    }
    // depth-4 max tree over the 8 pair-winners (parallel-issuable, short deps)
    const unsigned long long q0 = kp[0] > kp[1] ? kp[0] : kp[1];
    const unsigned long long q1 = kp[2] > kp[3] ? kp[2] : kp[3];
    const unsigned long long q2 = kp[4] > kp[5] ? kp[4] : kp[5];
    const unsigned long long q3 = kp[6] > kp[7] ? kp[6] : kp[7];
    const unsigned long long h0 = q0 > q1 ? q0 : q1;
    const unsigned long long h1 = q2 > q3 ? q2 : q3;
    unsigned long long key = h0 > h1 ? h0 : h1;

    // per-wave max: 6-stage DPP; full max lands in lane 63 -> write directly
    {
      unsigned long long t;
      t = dpp64<0x111>(key); key = t > key ? t : key;   // row_shr:1
      t = dpp64<0x112>(key); key = t > key ? t : key;   // row_shr:2
      t = dpp64<0x114>(key); key = t > key ? t : key;   // row_shr:4
      t = dpp64<0x118>(key); key = t > key ? t : key;   // row_shr:8
      t = dpp64<0x142>(key); key = t > key ? t : key;   // row_bcast:15
      t = dpp64<0x143>(key); key = t > key ? t : key;   // row_bcast:31
    }
    if (ln == 63) wred[buf][wv] = key;
    __syncthreads();                            // the ONLY barrier per iter
    // lane-parallel decode: lanes load the 8 wave keys, 3-stage DPP max,
    // read back only the low dword (n is all we need).
    unsigned long long kk = wred[buf][ln & 7];
    unsigned long long t;
    t = dpp64<0x111>(kk); kk = t > kk ? t : kk;
    t = dpp64<0x112>(kk); kk = t > kk ? t : kk;
    t = dpp64<0x114>(kk); kk = t > kk ? t : kk;
    const int nw = N_ - 1 -
        (int)(unsigned)__builtin_amdgcn_readlane((int)(unsigned)(kk & 0xFFFFFFFFull), 7);
    float4 cc = pc4[nw];                        // 1 broadcast b128
    cx = cc.x; cy = cc.y; cz = cc.z;
    if (tid == 0) idxHist[it] = nw;
    buf ^= 1;
  }
  __syncthreads();

  float* po = p_out + (size_t)b * M_ * 3;
  for (int mi = tid; mi < M_; mi += FTH) {
    float4 v = pc4[idxHist[mi]];
    po[mi * 3 + 0] = v.x;
    po[mi * 3 + 1] = v.y;
    po[mi * 3 + 2] = v.z;
  }
}

// ---------------------------------------------------------------------------
// 3) KNN — VERBATIM from the passing chain. 16 queries/block, p[b]+sn staged
//    in LDS once per block; per-lane sorted top-4 cache, 16 DPP-min rounds,
//    exact rescan; fused gather/max-pool. d2 bits identical.
// ---------------------------------------------------------------------------
#define UMAXK 0xFFFFFFFFFFFFFFFFull
#define QPB  16   // queries (waves) per block

__global__ __launch_bounds__(1024) void knn_kernel(
    const float* __restrict__ p, const float* __restrict__ p_out,
    const float* __restrict__ h, float* __restrict__ y) {
#pragma clang fp contract(off)
  __shared__ float4 pc4[N_];            // 128 KB: x,y,z,sn
  __shared__ int winLds[QPB][K_];

  const int t    = threadIdx.x;
  const int wv   = t >> 6;
  const int lane = t & 63;
  const int b    = blockIdx.x & 7;      // batch: keeps h[b] on one XCD (heur.)
  const int grp  = blockIdx.x >> 3;     // 0..127
  const int q    = b * M_ + grp * QPB + wv;

  const float* pb = p + (size_t)b * N_ * 3;
  for (int n = t; n < N_; n += 1024) {
    float xx = pb[3 * n + 0], yy = pb[3 * n + 1], zz = pb[3 * n + 2];
    float sn = (xx * xx + yy * yy) + zz * zz;   // numpy sum, no fma
    pc4[n] = make_float4(xx, yy, zz, sn);
  }
  __syncthreads();

  const float qx = p_out[q * 3 + 0];
  const float qy = p_out[q * 3 + 1];
  const float qz = p_out[q * 3 + 2];
  const float sq = (qx * qx + qy * qy) + qz * qz;   // numpy sum, no fma

  unsigned long long c0 = UMAXK, c1 = UMAXK, c2 = UMAXK, c3 = UMAXK;
#pragma unroll 4
  for (int j = 0; j < 128; j++) {
    const int n = lane + (j << 6);
    float4 v = pc4[n];
    float dot = __builtin_fmaf(qz, v.z,
                __builtin_fmaf(qy, v.y, qx * v.x)); // BLAS fma chain, k asc
    float d2 = (sq + v.w) - 2.0f * dot;
    unsigned u = __float_as_uint(d2);
    u ^= (unsigned)((int)u >> 31) | 0x80000000u;    // monotone f32->u32
    unsigned long long key = ((unsigned long long)u << 32) | (unsigned)n;
    if (key < c3) {
      unsigned long long x2 = key, mn;
      mn = x2 < c0 ? x2 : c0; x2 = x2 < c0 ? c0 : x2; c0 = mn;
      mn = x2 < c1 ? x2 : c1; x2 = x2 < c1 ? c1 : x2; c1 = mn;
      mn = x2 < c2 ? x2 : c2; x2 = x2 < c2 ? c2 : x2; c2 = mn;
      c3 = x2 < c3 ? x2 : c3;
    }
  }

  int count = 4;
  unsigned long long em0 = 0ull, em1 = 0ull;    // extraction mask (128 bits)
  unsigned long long mykey = UMAXK;             // lane r keeps round-r winner

  for (int k = 0; k < K_; k++) {
    unsigned long long cnd = (count > 0) ? c0 : UMAXK;
    unsigned long long win = wave_min_u64(cnd); // uniform; unique n => exact
    if (lane == k) mykey = win;
    const int nstar = (int)(unsigned)(win & 0xFFFFFFFFu);
    if ((nstar & 63) == lane) {                 // I own the winner (== my c0)
      const int j = nstar >> 6;
      if (j < 64) em0 |= 1ull << j; else em1 |= 1ull << (j - 64);
      c0 = c1; c1 = c2; c2 = c3; c3 = UMAXK; count--;
      if (count == 0 && k < K_ - 1) {           // rare exact rescan from LDS
        c0 = c1 = c2 = c3 = UMAXK;
        for (int j2 = 0; j2 < 128; j2++) {
          bool ex = (j2 < 64) ? ((em0 >> j2) & 1ull) : ((em1 >> (j2 - 64)) & 1ull);
          if (!ex) {
            const int n2 = lane + (j2 << 6);
            float4 v = pc4[n2];
            float dot = __builtin_fmaf(qz, v.z,
                        __builtin_fmaf(qy, v.y, qx * v.x));
            float d2 = (sq + v.w) - 2.0f * dot;
            unsigned u = __float_as_uint(d2);
            u ^= (unsigned)((int)u >> 31) | 0x80000000u;
            unsigned long long kk2 = ((unsigned long long)u << 32) | (unsigned)n2;
            if (kk2 < c3) {
              unsigned long long x2 = kk2, mn;
              mn = x2 < c0 ? x2 : c0; x2 = x2 < c0 ? c0 : x2; c0 = mn;
              mn = x2 < c1 ? x2 : c1; x2 = x2 < c1 ? c1 : x2; c1 = mn;
              mn = x2 < c2 ? x2 : c2; x2 = x2 < c2 ? c2 : x2; c2 = mn;
              c3 = x2 < c3 ? x2 : c3;
            }
          }
        }
        count = 4;
      }
    }
  }

  if (lane < K_) winLds[wv][lane] = (int)(unsigned)(mykey & 0xFFFFFFFFu);
  __syncthreads();

  const float* hb = h + (size_t)b * N_ * COUT;
  float2 acc = make_float2(-__builtin_inff(), -__builtin_inff());
#pragma unroll
  for (int i = 0; i < K_; i++) {
    const int n = winLds[wv][i];                // LDS broadcast read
    float2 v = *(const float2*)(hb + (size_t)n * COUT + lane * 2);
    acc.x = fmaxf(acc.x, v.x);
    acc.y = fmaxf(acc.y, v.y);
  }
  *(float2*)(y + (size_t)q * COUT + lane * 2) = acc;
}

// ---------------------------------------------------------------------------
extern "C" void kernel_launch(void* const* d_in, const int* in_sizes, int n_in,
                              void* d_out, int out_size, void* d_ws, size_t ws_size,
                              hipStream_t stream) {
  const float* x     = (const float*)d_in[0];
  const float* p     = (const float*)d_in[1];
  const float* W     = (const float*)d_in[2];
  const float* gamma = (const float*)d_in[3];
  const float* beta  = (const float*)d_in[4];
  const float* rmean = (const float*)d_in[5];
  const float* rvar  = (const float*)d_in[6];

  float* y     = (float*)d_out;                       // (B, M, COUT)
  float* p_out = y + (size_t)B_ * M_ * COUT;          // (B, M, 3)
  float* h     = (float*)d_ws;                        // (B, N, COUT) scratch

  fps_mlp_kernel<<<8 + (B_ * N_) / MROWS2, 512, 0, stream>>>(
      p, p_out, x, W, gamma, beta, rmean, rvar, h);
  knn_kernel<<<B_ * (M_ / QPB), 1024, 0, stream>>>(p, p_out, h, y);
}

// Round 2
// 1987.963 us; speedup vs baseline: 1.0917x; 1.0917x over previous
//
#include <hip/hip_runtime.h>

#define B_   8
#define N_   8192
#define CIN  64
#define COUT 128
#define M_   2048
#define K_   16

typedef float v2f __attribute__((ext_vector_type(2)));

// ---------------------------------------------------------------------------
// DPP wave-64 reduce helpers (VALU-only, no LDS latency).
// ---------------------------------------------------------------------------
template <int CTRL>
__device__ __forceinline__ unsigned long long dpp64(unsigned long long x) {
  int lo = (int)(unsigned)(x & 0xFFFFFFFFull);
  int hi = (int)(unsigned)(x >> 32);
  int dlo = __builtin_amdgcn_update_dpp(lo, lo, CTRL, 0xF, 0xF, false);
  int dhi = __builtin_amdgcn_update_dpp(hi, hi, CTRL, 0xF, 0xF, false);
  return ((unsigned long long)(unsigned)dhi << 32) | (unsigned)dlo;
}

__device__ __forceinline__ unsigned long long readlane_u64(unsigned long long k, int l) {
  unsigned lo = (unsigned)__builtin_amdgcn_readlane((int)(unsigned)(k & 0xFFFFFFFFull), l);
  unsigned hi = (unsigned)__builtin_amdgcn_readlane((int)(unsigned)(k >> 32), l);
  return ((unsigned long long)hi << 32) | lo;
}

__device__ __forceinline__ unsigned long long wave_min_u64(unsigned long long k) {
  unsigned long long t;
  t = dpp64<0x111>(k); k = t < k ? t : k;
  t = dpp64<0x112>(k); k = t < k ? t : k;
  t = dpp64<0x114>(k); k = t < k ? t : k;
  t = dpp64<0x118>(k); k = t < k ? t : k;
  t = dpp64<0x142>(k); k = t < k ? t : k;
  t = dpp64<0x143>(k); k = t < k ? t : k;
  return readlane_u64(k, 63);
}

// ---------------------------------------------------------------------------
// 1+2) Merged FPS + MLP kernel, R13: 256-thread blocks.
//      Blocks 0..7: FPS (one per batch), 4 waves x 32 pts/lane = 1 wave/SIMD.
//      The per-wave fixed overhead (local argmax + DPP reduce + decode) was
//      previously replicated across 8 waves (2/SIMD); now 4 waves amortize it
//      while pk distance work per SIMD is unchanged. Local argmax is a
//      running pk_max + 2 cndmask chain (5 instr/slot), strict > keeps the
//      smallest slot = smallest n within the lane; cross even/odd by slot
//      compare; cross-lane/wave by u64 (d_bits<<32 | 8191-n) max. Exactly
//      reference argmax (max d, first/min n) with bitwise-identical d.
//
//      Blocks 8..4103: MLP tiles (16 rows each, 256 threads) — fill the other
//      248 CUs while FPS grinds; per-row op order identical to the passing
//      chain (ascending c4, xv.x*w0 + xv.y*w1 + xv.z*w2 + xv.w*w3) so h is
//      bitwise identical.
//
//      FPS numerics: f32 strict numpy order ((dx^2+dy^2)+dz^2) NO-FMA
//      (contract off; pk ops elementwise IEEE identical), elementwise min.
// ---------------------------------------------------------------------------
#define FTH 256
#define FPT 32    // points per thread = N_/FTH
#define MROWS2 16 // rows per mlp block (256 threads)

__global__ __launch_bounds__(256) void fps_mlp_kernel(
    const float* __restrict__ p, float* __restrict__ p_out,
    const float* __restrict__ x, const float* __restrict__ W,
    const float* __restrict__ gamma, const float* __restrict__ beta,
    const float* __restrict__ rmean, const float* __restrict__ rvar,
    float* __restrict__ h) {
#pragma clang fp contract(off)
  __shared__ __align__(16) unsigned char smem[139776];

  const int tid = threadIdx.x;

  if (blockIdx.x >= 8) {
    // ---------------- MLP tile ----------------
    float* wt = (float*)smem;                   // W^T padded: wt[c*132+o]
    float* xs = (float*)(smem + 33792);         // xs[r*64+c], 16 rows

    const int o  = tid & 127;
    const int rg = tid >> 7;                    // 0..1 -> rows rg*8..rg*8+7
    const int rowBase = (blockIdx.x - 8) * MROWS2;

    for (int idx = tid; idx < COUT * CIN; idx += 256) {
      const int oo = idx >> 6, cc = idx & 63;
      wt[cc * 132 + oo] = W[idx];
    }
    ((float4*)xs)[tid] = ((const float4*)(x + (size_t)rowBase * CIN))[tid];
    __syncthreads();

    float acc[8] = {0.f, 0.f, 0.f, 0.f, 0.f, 0.f, 0.f, 0.f};
#pragma unroll
    for (int c4 = 0; c4 < CIN / 4; c4++) {
      const float w0 = wt[(4 * c4 + 0) * 132 + o];
      const float w1 = wt[(4 * c4 + 1) * 132 + o];
      const float w2 = wt[(4 * c4 + 2) * 132 + o];
      const float w3 = wt[(4 * c4 + 3) * 132 + o];
#pragma unroll
      for (int i = 0; i < 8; i++) {
        const float4 xv = *(const float4*)&xs[(rg * 8 + i) * CIN + c4 * 4];
        acc[i] += xv.x * w0 + xv.y * w1 + xv.z * w2 + xv.w * w3;
      }
    }
    const float mu = rmean[o];
    const float sc = rsqrtf(rvar[o] + 1e-5f) * gamma[o];
    const float bt = beta[o];
#pragma unroll
    for (int i = 0; i < 8; i++) {
      const float v = (acc[i] - mu) * sc + bt;
      h[(size_t)(rowBase + rg * 8 + i) * COUT + o] = fmaxf(v, 0.f);
    }
    return;
  }

  // ---------------- FPS ----------------
  float4* pc4 = (float4*)smem;                               // 128 KB
  unsigned long long (*wred)[8] =
      (unsigned long long (*)[8])(smem + 131072);            // 2*8*8 B
  int* idxHist = (int*)(smem + 131072 + 128);                // 8 KB

  const int b  = blockIdx.x;
  const int wv = tid >> 6;                                   // 0..3
  const int ln = tid & 63;

  const float* pb = p + (size_t)b * N_ * 3;
  for (int n = tid; n < N_; n += FTH)
    pc4[n] = make_float4(pb[3 * n + 0], pb[3 * n + 1], pb[3 * n + 2], 0.f);
  if (tid == 0) idxHist[0] = 0;
  __syncthreads();

  float4 c0 = pc4[0];
  float cx = c0.x, cy = c0.y, cz = c0.z;

  // pairs: element e of pair j is point n = tid + (2j+e)*256, slot s = 2j+e
  v2f X2[16], Y2[16], Z2[16], D2[16];
#pragma unroll
  for (int j = 0; j < 16; j++) {
    float4 a = pc4[tid + (2 * j) * FTH];
    float4 c = pc4[tid + (2 * j + 1) * FTH];
    X2[j] = (v2f){a.x, c.x};
    Y2[j] = (v2f){a.y, c.y};
    Z2[j] = (v2f){a.z, c.z};
    D2[j] = (v2f){__builtin_inff(), __builtin_inff()};
  }

  int buf = 0;
  for (int it = 1; it < M_; ++it) {
    const v2f cxv = {cx, cx}, cyv = {cy, cy}, czv = {cz, cz};
    v2f vbd = (v2f){-1.0f, -1.0f};     // all dm >= 0 -> slot 0/1 always wins
    int sx = 0, sy = 1;                // even-chain slot, odd-chain slot
#pragma unroll
    for (int j = 0; j < 16; j++) {
      v2f dx = X2[j] - cxv;
      v2f dy = Y2[j] - cyv;
      v2f dz = Z2[j] - czv;
      v2f m1 = dx * dx;
      v2f m2 = dy * dy;
      v2f s  = m1 + m2;
      v2f m3 = dz * dz;
      v2f d  = s + m3;                           // numpy order, no fma
      v2f dm = __builtin_elementwise_min(D2[j], d);
      D2[j] = dm;
      const bool gx = dm.x > vbd.x;              // strict > keeps first max
      const bool gy = dm.y > vbd.y;
      sx = gx ? (2 * j) : sx;
      sy = gy ? (2 * j + 1) : sy;
      vbd = __builtin_elementwise_max(vbd, dm);
    }
    // combine even/odd chains: larger d, tie -> smaller slot (= smaller n)
    float bd; int bk;
    if (vbd.y > vbd.x || (vbd.y == vbd.x && sy < sx)) { bd = vbd.y; bk = sy; }
    else                                               { bd = vbd.x; bk = sx; }
    const int n = tid + (bk << 8);
    unsigned long long key =
        ((unsigned long long)__float_as_uint(bd) << 32) |
        (unsigned)(N_ - 1 - n);                 // max key => max d, min n

    // per-wave max: 6-stage DPP; full max lands in lane 63 -> write directly
    {
      unsigned long long t;
      t = dpp64<0x111>(key); key = t > key ? t : key;   // row_shr:1
      t = dpp64<0x112>(key); key = t > key ? t : key;   // row_shr:2
      t = dpp64<0x114>(key); key = t > key ? t : key;   // row_shr:4
      t = dpp64<0x118>(key); key = t > key ? t : key;   // row_shr:8
      t = dpp64<0x142>(key); key = t > key ? t : key;   // row_bcast:15
      t = dpp64<0x143>(key); key = t > key ? t : key;   // row_bcast:31
    }
    if (ln == 63) wred[buf][wv] = key;
    __syncthreads();                            // the ONLY barrier per iter
    // lane-parallel decode: lanes load the 4 wave keys, 2-stage DPP max,
    // read back only the low dword (n is all we need).
    unsigned long long kk = wred[buf][ln & 3];
    unsigned long long t;
    t = dpp64<0x111>(kk); kk = t > kk ? t : kk;
    t = dpp64<0x112>(kk); kk = t > kk ? t : kk;
    const int nw = N_ - 1 -
        (int)(unsigned)__builtin_amdgcn_readlane((int)(unsigned)(kk & 0xFFFFFFFFull), 3);
    float4 cc = pc4[nw];                        // 1 broadcast b128
    cx = cc.x; cy = cc.y; cz = cc.z;
    if (tid == 0) idxHist[it] = nw;
    buf ^= 1;
  }
  __syncthreads();

  float* po = p_out + (size_t)b * M_ * 3;
  for (int mi = tid; mi < M_; mi += FTH) {
    float4 v = pc4[idxHist[mi]];
    po[mi * 3 + 0] = v.x;
    po[mi * 3 + 1] = v.y;
    po[mi * 3 + 2] = v.z;
  }
}

// ---------------------------------------------------------------------------
// 3) KNN — VERBATIM from the passing chain. 16 queries/block, p[b]+sn staged
//    in LDS once per block; per-lane sorted top-4 cache, 16 DPP-min rounds,
//    exact rescan; fused gather/max-pool. d2 bits identical.
// ---------------------------------------------------------------------------
#define UMAXK 0xFFFFFFFFFFFFFFFFull
#define QPB  16   // queries (waves) per block

__global__ __launch_bounds__(1024) void knn_kernel(
    const float* __restrict__ p, const float* __restrict__ p_out,
    const float* __restrict__ h, float* __restrict__ y) {
#pragma clang fp contract(off)
  __shared__ float4 pc4[N_];            // 128 KB: x,y,z,sn
  __shared__ int winLds[QPB][K_];

  const int t    = threadIdx.x;
  const int wv   = t >> 6;
  const int lane = t & 63;
  const int b    = blockIdx.x & 7;      // batch: keeps h[b] on one XCD (heur.)
  const int grp  = blockIdx.x >> 3;     // 0..127
  const int q    = b * M_ + grp * QPB + wv;

  const float* pb = p + (size_t)b * N_ * 3;
  for (int n = t; n < N_; n += 1024) {
    float xx = pb[3 * n + 0], yy = pb[3 * n + 1], zz = pb[3 * n + 2];
    float sn = (xx * xx + yy * yy) + zz * zz;   // numpy sum, no fma
    pc4[n] = make_float4(xx, yy, zz, sn);
  }
  __syncthreads();

  const float qx = p_out[q * 3 + 0];
  const float qy = p_out[q * 3 + 1];
  const float qz = p_out[q * 3 + 2];
  const float sq = (qx * qx + qy * qy) + qz * qz;   // numpy sum, no fma

  unsigned long long c0 = UMAXK, c1 = UMAXK, c2 = UMAXK, c3 = UMAXK;
#pragma unroll 4
  for (int j = 0; j < 128; j++) {
    const int n = lane + (j << 6);
    float4 v = pc4[n];
    float dot = __builtin_fmaf(qz, v.z,
                __builtin_fmaf(qy, v.y, qx * v.x)); // BLAS fma chain, k asc
    float d2 = (sq + v.w) - 2.0f * dot;
    unsigned u = __float_as_uint(d2);
    u ^= (unsigned)((int)u >> 31) | 0x80000000u;    // monotone f32->u32
    unsigned long long key = ((unsigned long long)u << 32) | (unsigned)n;
    if (key < c3) {
      unsigned long long x2 = key, mn;
      mn = x2 < c0 ? x2 : c0; x2 = x2 < c0 ? c0 : x2; c0 = mn;
      mn = x2 < c1 ? x2 : c1; x2 = x2 < c1 ? c1 : x2; c1 = mn;
      mn = x2 < c2 ? x2 : c2; x2 = x2 < c2 ? c2 : x2; c2 = mn;
      c3 = x2 < c3 ? x2 : c3;
    }
  }

  int count = 4;
  unsigned long long em0 = 0ull, em1 = 0ull;    // extraction mask (128 bits)
  unsigned long long mykey = UMAXK;             // lane r keeps round-r winner

  for (int k = 0; k < K_; k++) {
    unsigned long long cnd = (count > 0) ? c0 : UMAXK;
    unsigned long long win = wave_min_u64(cnd); // uniform; unique n => exact
    if (lane == k) mykey = win;
    const int nstar = (int)(unsigned)(win & 0xFFFFFFFFu);
    if ((nstar & 63) == lane) {                 // I own the winner (== my c0)
      const int j = nstar >> 6;
      if (j < 64) em0 |= 1ull << j; else em1 |= 1ull << (j - 64);
      c0 = c1; c1 = c2; c2 = c3; c3 = UMAXK; count--;
      if (count == 0 && k < K_ - 1) {           // rare exact rescan from LDS
        c0 = c1 = c2 = c3 = UMAXK;
        for (int j2 = 0; j2 < 128; j2++) {
          bool ex = (j2 < 64) ? ((em0 >> j2) & 1ull) : ((em1 >> (j2 - 64)) & 1ull);
          if (!ex) {
            const int n2 = lane + (j2 << 6);
            float4 v = pc4[n2];
            float dot = __builtin_fmaf(qz, v.z,
                        __builtin_fmaf(qy, v.y, qx * v.x));
            float d2 = (sq + v.w) - 2.0f * dot;
            unsigned u = __float_as_uint(d2);
            u ^= (unsigned)((int)u >> 31) | 0x80000000u;
            unsigned long long kk2 = ((unsigned long long)u << 32) | (unsigned)n2;
            if (kk2 < c3) {
              unsigned long long x2 = kk2, mn;
              mn = x2 < c0 ? x2 : c0; x2 = x2 < c0 ? c0 : x2; c0 = mn;
              mn = x2 < c1 ? x2 : c1; x2 = x2 < c1 ? c1 : x2; c1 = mn;
              mn = x2 < c2 ? x2 : c2; x2 = x2 < c2 ? c2 : x2; c2 = mn;
              c3 = x2 < c3 ? x2 : c3;
            }
          }
        }
        count = 4;
      }
    }
  }

  if (lane < K_) winLds[wv][lane] = (int)(unsigned)(mykey & 0xFFFFFFFFu);
  __syncthreads();

  const float* hb = h + (size_t)b * N_ * COUT;
  float2 acc = make_float2(-__builtin_inff(), -__builtin_inff());
#pragma unroll
  for (int i = 0; i < K_; i++) {
    const int n = winLds[wv][i];                // LDS broadcast read
    float2 v = *(const float2*)(hb + (size_t)n * COUT + lane * 2);
    acc.x = fmaxf(acc.x, v.x);
    acc.y = fmaxf(acc.y, v.y);
  }
  *(float2*)(y + (size_t)q * COUT + lane * 2) = acc;
}

// ---------------------------------------------------------------------------
extern "C" void kernel_launch(void* const* d_in, const int* in_sizes, int n_in,
                              void* d_out, int out_size, void* d_ws, size_t ws_size,
                              hipStream_t stream) {
  const float* x     = (const float*)d_in[0];
  const float* p     = (const float*)d_in[1];
  const float* W     = (const float*)d_in[2];
  const float* gamma = (const float*)d_in[3];
  const float* beta  = (const float*)d_in[4];
  const float* rmean = (const float*)d_in[5];
  const float* rvar  = (const float*)d_in[6];

  float* y     = (float*)d_out;                       // (B, M, COUT)
  float* p_out = y + (size_t)B_ * M_ * COUT;          // (B, M, 3)
  float* h     = (float*)d_ws;                        // (B, N, COUT) scratch

  fps_mlp_kernel<<<8 + (B_ * N_) / MROWS2, 256, 0, stream>>>(
      p, p_out, x, W, gamma, beta, rmean, rvar, h);
  knn_kernel<<<B_ * (M_ / QPB), 1024, 0, stream>>>(p, p_out, h, y);
}